// Round 6
// baseline (85.284 us; speedup 1.0000x reference)
//
#include <hip/hip_runtime.h>
#include <hip/hip_bf16.h>

typedef unsigned short u16;
typedef __attribute__((ext_vector_type(8))) __bf16 bf16x8;
typedef __attribute__((ext_vector_type(4))) float f32x4;

#define B_SZ 4096
#define D_SZ 1024
#define MARGIN 0.2f

__device__ __forceinline__ u16 f2bf(float x) {
  __hip_bfloat16 h = __float2bfloat16(x);
  u16 r; __builtin_memcpy(&r, &h, 2); return r;
}

// ---------------- normalize + cast to bf16 + diag ----------------
__global__ void norm_diag_kernel(const float* __restrict__ im,
                                 const float* __restrict__ tx,
                                 u16* __restrict__ imn,
                                 u16* __restrict__ txn,
                                 float* __restrict__ diag) {
  const int row = blockIdx.x;
  const int t = threadIdx.x;
  const size_t base = (size_t)row * D_SZ;
  float4 vi = reinterpret_cast<const float4*>(im + base)[t];
  float4 vt = reinterpret_cast<const float4*>(tx + base)[t];
  float ssi = vi.x * vi.x + vi.y * vi.y + vi.z * vi.z + vi.w * vi.w;
  float sst = vt.x * vt.x + vt.y * vt.y + vt.z * vt.z + vt.w * vt.w;
  float dot = vi.x * vt.x + vi.y * vt.y + vi.z * vt.z + vi.w * vt.w;
#pragma unroll
  for (int off = 32; off > 0; off >>= 1) {
    ssi += __shfl_down(ssi, off, 64);
    sst += __shfl_down(sst, off, 64);
    dot += __shfl_down(dot, off, 64);
  }
  __shared__ float w[3][4];
  if ((t & 63) == 0) { int wi = t >> 6; w[0][wi] = ssi; w[1][wi] = sst; w[2][wi] = dot; }
  __syncthreads();
  const float tssi = (w[0][0] + w[0][1]) + (w[0][2] + w[0][3]);
  const float tsst = (w[1][0] + w[1][1]) + (w[1][2] + w[1][3]);
  const float tdot = (w[2][0] + w[2][1]) + (w[2][2] + w[2][3]);
  const float si = 1.0f / fmaxf(sqrtf(tssi), 1e-12f);
  const float st = 1.0f / fmaxf(sqrtf(tsst), 1e-12f);
  u16 oi[4] = { f2bf(vi.x * si), f2bf(vi.y * si), f2bf(vi.z * si), f2bf(vi.w * si) };
  u16 ot[4] = { f2bf(vt.x * st), f2bf(vt.y * st), f2bf(vt.z * st), f2bf(vt.w * st) };
  ushort4 pi, pt; __builtin_memcpy(&pi, oi, 8); __builtin_memcpy(&pt, ot, 8);
  reinterpret_cast<ushort4*>(imn + base)[t] = pi;
  reinterpret_cast<ushort4*>(txn + base)[t] = pt;
  if (t == 0) diag[row] = tdot * si * st;
}

// ---------------- 256x256 8-phase GEMM + fused hinge-loss epilogue ----------
// Round-6: 128-BYTE-PITCH LDS regions + guide-exact XOR swizzle.
// 8 regions of [128 rows][64 cols bf16] (16 KiB each): [buf][A0,A1,B0,B1].
//   A_mg holds rows {wr*128+mg*64 ..+64} for wr=0,1 (region-row = wr*64+r).
//   B_ng holds rows {wc*64+ng*32 ..+32} for wc=0..3 (region-row = wc*32+r).
// Swizzle: stored 16B-slot = nominal_slot ^ (region_row & 7); staging source
// pre-swizzled with the same involution (cb = (l&7) ^ (l>>3)), gload_lds dest
// stays linear (rule #21).
// Iter = 2 K-tiles, 8 quadrant phases (mg,ng); 12 ds_reads + 1 stage-unit
// (2 gload_lds) per phase; vmcnt(4) gates at phases 4 and 8 only.
__device__ __forceinline__ void gload_lds16(const u16* g, u16* l) {
  __builtin_amdgcn_global_load_lds((__attribute__((address_space(1))) void*)g,
                                   (__attribute__((address_space(3))) void*)l,
                                   16, 0, 0);
}

#define BAR() __builtin_amdgcn_s_barrier()
#define LGKM(n) asm volatile("s_waitcnt lgkmcnt(" #n ")" ::: "memory")
#define VMC(n) asm volatile("s_waitcnt vmcnt(" #n ")" ::: "memory")

__global__ __launch_bounds__(512, 2) void gemm_loss_kernel(
    const u16* __restrict__ A,   // imn [4096][1024]
    const u16* __restrict__ Bt,  // txn [4096][1024]
    const float* __restrict__ diag,
    float* __restrict__ sim,     // d_out+1, row-major [4096][4096]
    float* __restrict__ loss) {
  __shared__ u16 sm[65536];      // 8 regions x 8192 el

  const int tid = threadIdx.x;
  const int l = tid & 63;
  const int w = tid >> 6;        // wave 0..7
  const int wr = w >> 2;         // 0..1  (M half)
  const int wc = w & 3;          // 0..3  (N quarter)
  const int ar = l & 15;
  const int arh = l >> 4;        // 0..3

  // XCD-aware bijective swizzle: 256 blocks, 8 XCDs, 32 consecutive per XCD.
  const int bid = blockIdx.x;
  const int s = (bid & 7) * 32 + (bid >> 3);
  const int tm = (s >> 4) * 256;
  const int tn = (s & 15) * 256;

  f32x4 acc[8][4] = {};

  // ---- staging addressing (pre-swizzled global source) ----
  const int l3 = l >> 3;               // 0..7
  const int cb = (l & 7) ^ l3;         // swizzled source col-block (involution)
  const u16* pA[2][2];                 // [mg][chunk]
  const u16* pB[2][2];                 // [ng][chunk]
#pragma unroll
  for (int c = 0; c < 2; c++) {
    const int rho = w * 16 + c * 8 + l3;     // region-row 0..127
#pragma unroll
    for (int mg = 0; mg < 2; mg++)
      pA[mg][c] = A + (size_t)(tm + (rho >> 6) * 128 + mg * 64 + (rho & 63)) * D_SZ + cb * 8;
#pragma unroll
    for (int ng = 0; ng < 2; ng++)
      pB[ng][c] = Bt + (size_t)(tn + (rho >> 5) * 64 + ng * 32 + (rho & 31)) * D_SZ + cb * 8;
  }

  auto SA = [&](int mg, int kt, int buf) {
    u16* d = sm + (buf * 4 + mg) * 8192 + w * 1024;
    gload_lds16(pA[mg][0] + kt * 64, d);
    gload_lds16(pA[mg][1] + kt * 64, d + 512);
  };
  auto SB = [&](int ng, int kt, int buf) {
    u16* d = sm + (buf * 4 + 2 + ng) * 8192 + w * 1024;
    gload_lds16(pB[ng][0] + kt * 64, d);
    gload_lds16(pB[ng][1] + kt * 64, d + 512);
  };

  // ---- LDS read offsets (swizzled slot = (ks*4+arh) ^ (row&7)) ----
  const int sl0 = ((arh) ^ (ar & 7)) * 8;        // ks=0
  const int sl1 = ((4 + arh) ^ (ar & 7)) * 8;    // ks=1
  const int aB = (wr * 64 + ar) * 64;
  const int bB = (wc * 32 + ar) * 64;

#define PHASE(mg, ng, buf, STAGECALL, GATE) do {                              \
    const u16* Ar = sm + ((buf) * 4 + (mg)) * 8192 + aB;                      \
    const u16* Br = sm + ((buf) * 4 + 2 + (ng)) * 8192 + bB;                  \
    bf16x8 a_[4][2], b_[2][2];                                                \
    _Pragma("unroll")                                                         \
    for (int m = 0; m < 4; m++) {                                             \
      a_[m][0] = *(const bf16x8*)&Ar[m * 1024 + sl0];                         \
      a_[m][1] = *(const bf16x8*)&Ar[m * 1024 + sl1];                         \
    }                                                                         \
    _Pragma("unroll")                                                         \
    for (int n = 0; n < 2; n++) {                                             \
      b_[n][0] = *(const bf16x8*)&Br[n * 1024 + sl0];                         \
      b_[n][1] = *(const bf16x8*)&Br[n * 1024 + sl1];                         \
    }                                                                         \
    STAGECALL;                                                                \
    LGKM(8);                                                                  \
    BAR();                                                                    \
    LGKM(0);                                                                  \
    __builtin_amdgcn_s_setprio(1);                                            \
    _Pragma("unroll")                                                         \
    for (int m = 0; m < 4; m++)                                               \
      _Pragma("unroll")                                                       \
      for (int n = 0; n < 2; n++) {                                           \
        acc[(mg) * 4 + m][(ng) * 2 + n] =                                     \
            __builtin_amdgcn_mfma_f32_16x16x32_bf16(                          \
                a_[m][0], b_[n][0], acc[(mg) * 4 + m][(ng) * 2 + n], 0, 0, 0);\
        acc[(mg) * 4 + m][(ng) * 2 + n] =                                     \
            __builtin_amdgcn_mfma_f32_16x16x32_bf16(                          \
                a_[m][1], b_[n][1], acc[(mg) * 4 + m][(ng) * 2 + n], 0, 0, 0);\
      }                                                                       \
    __builtin_amdgcn_s_setprio(0);                                            \
    GATE;                                                                     \
    BAR();                                                                    \
  } while (0)

  // ---- prologue: tile0 complete + A0/B0 of tile1 (12 loads) ----
  SA(0, 0, 0); SB(0, 0, 0); SB(1, 0, 0); SA(1, 0, 0);
  SA(0, 1, 1); SB(0, 1, 1);
  VMC(4);                      // tile 0's 8 loads landed; tile 1's 4 in flight
  BAR();

  // ---- main loop: 8 iters x 2 K-tiles ----
#pragma unroll 1
  for (int i = 0; i < 8; ++i) {
    const int t1 = 2 * i + 1;
    const int k2 = (2 * i + 2 < 16) ? 2 * i + 2 : 15;   // clamp keeps vmcnt
    const int k3 = (2 * i + 3 < 16) ? 2 * i + 3 : 15;   // counts exact
    PHASE(0, 0, 0, (SA(1, t1, 1)), (void)0);
    PHASE(0, 1, 0, (SB(1, t1, 1)), (void)0);
    PHASE(1, 0, 0, (SA(0, k2, 0)), (void)0);
    PHASE(1, 1, 0, (SB(0, k2, 0)), VMC(4));
    PHASE(0, 0, 1, (SA(1, k2, 0)), (void)0);
    PHASE(0, 1, 1, (SB(1, k2, 0)), (void)0);
    PHASE(1, 0, 1, (SA(0, k3, 1)), (void)0);
    PHASE(1, 1, 1, (SB(0, k3, 1)), VMC(4));
  }
  VMC(0);                      // drain tail stages before LDS dealloc

  // ---- C-write + hinge loss ----
  float dcs[4];
#pragma unroll
  for (int n = 0; n < 4; n++) dcs[n] = diag[tn + wc * 64 + n * 16 + ar];
  float lsum = 0.f;
#pragma unroll
  for (int m = 0; m < 8; m++) {
#pragma unroll
    for (int i = 0; i < 4; i++) {
      const int r = tm + wr * 128 + m * 16 + arh * 4 + i;
      const float dr = diag[r];
#pragma unroll
      for (int n = 0; n < 4; n++) {
        const int c = tn + wc * 64 + n * 16 + ar;
        const float s_ = acc[m][n][i];
        sim[(size_t)r * B_SZ + c] = s_;
        if (r != c)
          lsum += fmaxf(MARGIN + s_ - dr, 0.f) + fmaxf(MARGIN + s_ - dcs[n], 0.f);
      }
    }
  }
#pragma unroll
  for (int off = 32; off > 0; off >>= 1) lsum += __shfl_down(lsum, off, 64);
  if (l == 0) atomicAdd(loss, lsum);
#undef PHASE
}

extern "C" void kernel_launch(void* const* d_in, const int* in_sizes, int n_in,
                              void* d_out, int out_size, void* d_ws, size_t ws_size,
                              hipStream_t stream) {
  const float* im = (const float*)d_in[0];
  const float* tx = (const float*)d_in[1];
  float* out = (float*)d_out;
  float* loss = out;        // output 0: scalar total_loss
  float* sim = out + 1;     // output 1: [4096][4096]

  u16* imn = (u16*)d_ws;
  u16* txn = imn + (size_t)B_SZ * D_SZ;
  float* diag = (float*)(txn + (size_t)B_SZ * D_SZ);

  hipMemsetAsync(d_out, 0, sizeof(float), stream);
  norm_diag_kernel<<<B_SZ, 256, 0, stream>>>(im, tx, imn, txn, diag);
  gemm_loss_kernel<<<(B_SZ / 256) * (B_SZ / 256), 512, 0, stream>>>(imn, txn, diag, sim, loss);
}